// Round 1
// baseline (1200.323 us; speedup 1.0000x reference)
//
#include <hip/hip_runtime.h>
#include <stdint.h>

// Sizes (fixed by the problem)
#define NB 256
#define NS 64
#define NR 256
#define NV 2000
#define NC 10
#define NK 6
#define ND 256

__device__ __forceinline__ float bf2f(uint16_t u) {
  return __uint_as_float(((uint32_t)u) << 16);
}
__device__ __forceinline__ uint16_t f2bf(float f) {
  uint32_t x = __float_as_uint(f);
  x += 0x7FFFu + ((x >> 16) & 1u);
  return (uint16_t)(x >> 16);
}

// ---------------------------------------------------------------------------
// k_prep: block 0 = adjacency dtype-detect + bitmask + neighbor lists + class
//         lists; blocks 1..10 = ud2/us2 = W2[c] @ a2{d,s}
// ---------------------------------------------------------------------------
__global__ void k_prep(const void* __restrict__ adj_raw, const int* __restrict__ mask,
                       const float* __restrict__ W2, const float* __restrict__ a2s,
                       const float* __restrict__ a2d,
                       uint32_t* __restrict__ adjbits, int* __restrict__ cls,
                       int* __restrict__ lists, int* __restrict__ cnt,
                       int* __restrict__ deg, uint8_t* __restrict__ nbr,
                       float* __restrict__ ud2, float* __restrict__ us2)
{
  int tid = threadIdx.x;
  if (blockIdx.x == 0) {
    __shared__ int s_is4;
    if (tid == 0) s_is4 = 1;
    __syncthreads();
    const uint32_t* u = (const uint32_t*)adj_raw;
    int ok = 1;
    for (int idx = tid; idx < 16384; idx += 256) {
      uint32_t v = u[idx];
      if (!(v == 0u || v == 1u || v == 0x3F800000u)) ok = 0;
    }
    if (!ok) atomicAnd(&s_is4, 0);
    __syncthreads();
    int is4 = s_is4;
    const uint8_t* b8 = (const uint8_t*)adj_raw;
    int dg = 0;
    for (int w = 0; w < 8; ++w) {
      uint32_t word = 0;
      for (int jb = 0; jb < 32; ++jb) {
        int j = w * 32 + jb;
        int bit = is4 ? (u[tid * 256 + j] != 0u) : (b8[tid * 256 + j] != 0);
        if (bit) {
          word |= (1u << jb);
          if (dg < 64) nbr[tid * 64 + dg] = (uint8_t)j;
          dg++;
        }
      }
      adjbits[tid * 8 + w] = word;
    }
    deg[tid] = (dg > 64) ? 64 : dg;
    int c = 0;
    for (int cc = 0; cc < NC; ++cc) if (mask[cc * 256 + tid] != 0) c = cc;
    cls[tid] = c;
    __syncthreads();
    if (tid == 0) {
      int cn[NC];
      for (int i = 0; i < NC; ++i) cn[i] = 0;
      for (int r = 0; r < 256; ++r) {
        int cc = cls[r];
        if (cn[cc] < 64) lists[cc * 64 + cn[cc]] = r;
        cn[cc]++;
      }
      for (int i = 0; i < NC; ++i) cnt[i] = (cn[i] > 64) ? 64 : cn[i];
    }
  } else {
    int c = blockIdx.x - 1;
    if (tid < 128) {
      float s1 = 0.f, s2 = 0.f;
      for (int g = 0; g < 64; ++g) {
        float w = W2[(c * 128 + tid) * 64 + g];
        s1 += w * a2d[c * 64 + g];
        s2 += w * a2s[c * 64 + g];
      }
      ud2[c * 128 + tid] = s1;
      us2[c * 128 + tid] = s2;
    }
  }
}

// ---------------------------------------------------------------------------
// k_ruleq: rule row r = basic[r]@Wtb + crucial[r]@Wtk + biases  (sparse 0/1
// rows -> ballot-compacted nnz list), then Q[r] = rule@Wq + bq
// ---------------------------------------------------------------------------
__global__ void k_ruleq(const float* __restrict__ basic, const float* __restrict__ cruc,
                        const float* __restrict__ Wtb, const float* __restrict__ btb,
                        const float* __restrict__ Wtk, const float* __restrict__ btk,
                        const float* __restrict__ Wq, const float* __restrict__ bq,
                        float* __restrict__ Qout)
{
  __shared__ float row_s[2048];
  __shared__ float rule_s[256];
  __shared__ int   nzi[128];
  __shared__ float nzv[128];
  __shared__ int   nzc;
  int tid = threadIdx.x, r = blockIdx.x;
  float acc = btb[tid] + btk[tid];
  for (int m = 0; m < 2; ++m) {
    const float* src = m ? cruc : basic;
    const float* W   = m ? Wtk : Wtb;
    for (int idx = tid; idx < 2048; idx += 256)
      row_s[idx] = (idx < NV) ? src[r * NV + idx] : 0.0f;
    if (tid == 0) nzc = 0;
    __syncthreads();
    if (tid < 64) {
      int base = 0;
      for (int ch = 0; ch < 32; ++ch) {
        int idx = ch * 64 + tid;
        float v = row_s[idx];
        unsigned long long bm = __ballot(v != 0.0f);
        if (v != 0.0f) {
          int pos = base + (int)__popcll(bm & ((1ull << tid) - 1ull));
          if (pos < 128) { nzi[pos] = idx; nzv[pos] = v; }
        }
        base += (int)__popcll(bm);
      }
      if (tid == 0) nzc = (base > 128) ? 128 : base;
    }
    __syncthreads();
    int n = nzc;
    for (int t = 0; t < n; ++t) acc += nzv[t] * W[nzi[t] * 256 + tid];
    __syncthreads();
  }
  rule_s[tid] = acc;
  __syncthreads();
  float q = bq[tid];
  for (int k2 = 0; k2 < 256; ++k2) q += rule_s[k2] * Wq[k2 * 256 + tid];
  Qout[r * 256 + tid] = q;
}

// ---------------------------------------------------------------------------
// k_kvproj: Kx/Vx = vis_emb @ Wk/Wv + bias, stored bf16
// ---------------------------------------------------------------------------
__global__ void k_kvproj(const float* __restrict__ vis, const float* __restrict__ Wk,
                         const float* __restrict__ bk, const float* __restrict__ Wv,
                         const float* __restrict__ bv,
                         uint16_t* __restrict__ KX, uint16_t* __restrict__ VX)
{
  __shared__ float vis_s[16][256];
  int tid = threadIdx.x;
  int row0 = blockIdx.x * 16;
  for (int idx = tid; idx < 16 * 256; idx += 256)
    vis_s[idx >> 8][idx & 255] = vis[(long)(row0 + (idx >> 8)) * 256 + (idx & 255)];
  __syncthreads();
  float aK[16], aV[16];
  #pragma unroll
  for (int j = 0; j < 16; ++j) { aK[j] = 0.f; aV[j] = 0.f; }
  for (int k2 = 0; k2 < 256; ++k2) {
    float wk = Wk[k2 * 256 + tid], wv = Wv[k2 * 256 + tid];
    #pragma unroll
    for (int j = 0; j < 16; ++j) { float e = vis_s[j][k2]; aK[j] += e * wk; aV[j] += e * wv; }
  }
  float bkv = bk[tid], bvv = bv[tid];
  #pragma unroll
  for (int j = 0; j < 16; ++j) {
    KX[(long)(row0 + j) * 256 + tid] = f2bf(aK[j] + bkv);
    VX[(long)(row0 + j) * 256 + tid] = f2bf(aV[j] + bvv);
  }
}

// ---------------------------------------------------------------------------
// k_attn: per (b, half of rules): 4 heads, QK^T/8 -> softmax(S=64) -> @V
// writes emb_pre (bf16)
// ---------------------------------------------------------------------------
__global__ __launch_bounds__(128) void k_attn(const float* __restrict__ Q,
                         const uint16_t* __restrict__ KX, const uint16_t* __restrict__ VX,
                         uint16_t* __restrict__ EMB)
{
  __shared__ float K_s[64][65];
  __shared__ float V_s[64][65];
  __shared__ float qa_s[128][65];
  int tid = threadIdx.x;
  int b = blockIdx.x >> 1;
  int rbase = (blockIdx.x & 1) << 7;
  int r = rbase + tid;
  for (int h = 0; h < 4; ++h) {
    __syncthreads();
    for (int idx = tid; idx < 4096; idx += 128) {
      int s = idx >> 6, d2 = idx & 63;
      long gi = ((long)(b * 64 + s)) * 256 + h * 64 + d2;
      K_s[s][d2] = bf2f(KX[gi]);
      V_s[s][d2] = bf2f(VX[gi]);
    }
    for (int idx = tid; idx < 8192; idx += 128) {
      int t = idx >> 6, d2 = idx & 63;
      qa_s[t][d2] = Q[(rbase + t) * 256 + h * 64 + d2];
    }
    __syncthreads();
    float att[64];
    #pragma unroll
    for (int s2 = 0; s2 < 64; ++s2) att[s2] = 0.f;
    for (int d2 = 0; d2 < 64; ++d2) {
      float qd = qa_s[tid][d2];
      #pragma unroll
      for (int s2 = 0; s2 < 64; ++s2) att[s2] += qd * K_s[s2][d2];
    }
    float m = att[0];
    #pragma unroll
    for (int s2 = 1; s2 < 64; ++s2) m = fmaxf(m, att[s2]);
    float sum = 0.f;
    #pragma unroll
    for (int s2 = 0; s2 < 64; ++s2) { att[s2] = __expf((att[s2] - m) * 0.125f); sum += att[s2]; }
    float rs = 1.0f / sum;
    #pragma unroll
    for (int s2 = 0; s2 < 64; ++s2) qa_s[tid][s2] = att[s2] * rs;
    float o[64];
    #pragma unroll
    for (int d2 = 0; d2 < 64; ++d2) o[d2] = 0.f;
    for (int s2 = 0; s2 < 64; ++s2) {
      float a = qa_s[tid][s2];
      #pragma unroll
      for (int d2 = 0; d2 < 64; ++d2) o[d2] += a * V_s[s2][d2];
    }
    long obase = ((long)(b * 256 + r)) * 256 + h * 64;
    for (int d2 = 0; d2 < 64; d2 += 2) {
      uint32_t pk = (uint32_t)f2bf(o[d2]) | ((uint32_t)f2bf(o[d2 + 1]) << 16);
      *(uint32_t*)(&EMB[obase + d2]) = pk;
    }
  }
}

// ---------------------------------------------------------------------------
// k_wo: emb = emb_pre @ Wo + bo   (in-place on bf16 EMB, rows staged first)
// ---------------------------------------------------------------------------
__global__ void k_wo(uint16_t* __restrict__ EMB, const float* __restrict__ Wo,
                     const float* __restrict__ bo)
{
  __shared__ float ep[32][256];
  int tid = threadIdx.x;
  long row0 = (long)blockIdx.x * 32;
  for (int idx = tid; idx < 32 * 256; idx += 256)
    ep[idx >> 8][idx & 255] = bf2f(EMB[(row0 + (idx >> 8)) * 256 + (idx & 255)]);
  __syncthreads();
  float acc[32];
  #pragma unroll
  for (int j = 0; j < 32; ++j) acc[j] = 0.f;
  for (int k2 = 0; k2 < 256; ++k2) {
    float w = Wo[k2 * 256 + tid];
    #pragma unroll
    for (int j = 0; j < 32; ++j) acc[j] += ep[j][k2] * w;
  }
  float bb = bo[tid];
  #pragma unroll
  for (int j = 0; j < 32; ++j) EMB[(row0 + j) * 256 + tid] = f2bf(acc[j] + bb);
}

// ---------------------------------------------------------------------------
// k_hw1: grouped GEMM hW1[b,r] = emb[b,r] @ W1[cls[r]] (only class-member
// rows, per (c,b) block) + e1d/e1s = hW1 . a1{d,s}[c]
// ---------------------------------------------------------------------------
__global__ __launch_bounds__(128) void k_hw1(const uint16_t* __restrict__ EMB,
                      const float* __restrict__ W1,
                      const float* __restrict__ a1d, const float* __restrict__ a1s,
                      const int* __restrict__ lists, const int* __restrict__ cnt,
                      uint16_t* __restrict__ HW1, float* __restrict__ e1d,
                      float* __restrict__ e1s)
{
  __shared__ float es[16][256];
  __shared__ float hw[16][129];
  __shared__ float va1d[128], va1s[128];
  __shared__ int rows[16];
  int tid = threadIdx.x;
  int c = blockIdx.x >> 8, b = blockIdx.x & 255;
  int n = cnt[c];
  va1d[tid] = a1d[c * 128 + tid];
  va1s[tid] = a1s[c * 128 + tid];
  for (int ch = 0; ch * 16 < n; ++ch) {
    __syncthreads();
    if (tid < 16) rows[tid] = (ch * 16 + tid < n) ? lists[c * 64 + ch * 16 + tid] : -1;
    __syncthreads();
    for (int idx = tid; idx < 16 * 256; idx += 128) {
      int j = idx >> 8, k2 = idx & 255;
      int rj = rows[j];
      es[j][k2] = (rj >= 0) ? bf2f(EMB[((long)b * 256 + rj) * 256 + k2]) : 0.0f;
    }
    __syncthreads();
    float acc[16];
    #pragma unroll
    for (int j = 0; j < 16; ++j) acc[j] = 0.f;
    for (int k2 = 0; k2 < 256; ++k2) {
      float w = W1[((long)c * 256 + k2) * 128 + tid];
      #pragma unroll
      for (int j = 0; j < 16; ++j) acc[j] += es[j][k2] * w;
    }
    #pragma unroll
    for (int j = 0; j < 16; ++j) {
      hw[j][tid] = acc[j];
      int rj = rows[j];
      if (rj >= 0) HW1[((long)b * 256 + rj) * 128 + tid] = f2bf(acc[j]);
    }
    __syncthreads();
    if (tid < 16) {
      int rj = rows[tid];
      if (rj >= 0) {
        float d1 = 0.f, d2 = 0.f;
        for (int d3 = 0; d3 < 128; ++d3) {
          float hv = hw[tid][d3];
          d1 += hv * va1d[d3];
          d2 += hv * va1s[d3];
        }
        e1d[(long)b * 256 + rj] = d1;
        e1s[(long)b * 256 + rj] = d2;
      }
    }
  }
}

// ---------------------------------------------------------------------------
// k_gat: per (c,b): sparse GAT1 aggregation over class members, relu+b1,
// collapsed GAT2 (e2 via precomputed ud2/us2, colsum via alpha2 col-weights),
// final log_softmax -> out[c,b,:]
// ---------------------------------------------------------------------------
__global__ __launch_bounds__(256) void k_gat(
    const uint16_t* __restrict__ HW1, const float* __restrict__ e1d_g,
    const float* __restrict__ e1s_g, const uint32_t* __restrict__ adjbits,
    const int* __restrict__ cls_g, const int* __restrict__ lists,
    const int* __restrict__ cnt_g, const int* __restrict__ deg_g,
    const uint8_t* __restrict__ nbr_g,
    const float* __restrict__ b1, const float* __restrict__ ud2_g,
    const float* __restrict__ us2_g, const float* __restrict__ W2,
    const float* __restrict__ b2, const float* __restrict__ Wl,
    const float* __restrict__ bl, float* __restrict__ out)
{
  __shared__ uint32_t adj_s[256][9];
  __shared__ uint8_t  nbr_s[256][68];
  __shared__ float hw_s[64][130];
  __shared__ float e1s_s[256];
  __shared__ float e2s_s[256], e2d_s[256], m2_s[256], dr2_s[256];
  __shared__ float t4[4][128];
  __shared__ float t_s[128];
  __shared__ float svec[64];
  __shared__ float lvec[8];
  __shared__ float b1_s[128], ud2_s[128], us2_s[128];
  __shared__ int   list_s[64];
  int tid = threadIdx.x;
  int c = blockIdx.x >> 8, b = blockIdx.x & 255;
  int n = cnt_g[c];
  for (int idx = tid; idx < 2048; idx += 256) adj_s[idx >> 3][idx & 7] = adjbits[idx];
  for (int idx = tid; idx < 256 * 64; idx += 256) nbr_s[idx >> 6][idx & 63] = nbr_g[idx];
  for (int idx = tid; idx < n * 128; idx += 256) {
    int jm = idx >> 7, d3 = idx & 127;
    hw_s[jm][d3] = bf2f(HW1[((long)b * 256 + lists[c * 64 + jm]) * 128 + d3]);
  }
  if (tid < 64) list_s[tid] = lists[c * 64 + tid];
  if (tid < 128) {
    b1_s[tid]  = b1[c * 128 + tid];
    ud2_s[tid] = ud2_g[c * 128 + tid];
    us2_s[tid] = us2_g[c * 128 + tid];
  }
  int myc = cls_g[tid];
  float e1d_i = (myc == c) ? e1d_g[(long)b * 256 + tid] : 0.0f;
  e1s_s[tid]  = (myc == c) ? e1s_g[(long)b * 256 + tid] : 0.0f;
  int dg = deg_g[tid];
  __syncthreads();
  // layer-1 softmax stats over neighbors
  float m1 = -1e30f;
  for (int t = 0; t < dg; ++t) {
    int j = nbr_s[tid][t];
    float e = e1d_i + e1s_s[j];
    e = fmaxf(e, 0.2f * e);
    m1 = fmaxf(m1, e);
  }
  float den = 0.f;
  for (int t = 0; t < dg; ++t) {
    int j = nbr_s[tid][t];
    float e = e1d_i + e1s_s[j];
    e = fmaxf(e, 0.2f * e);
    den += __expf(e - m1);
  }
  float rden = 1.0f / den;
  // layer-1 aggregation over class members (only they have nonzero hW1)
  float g[128];
  #pragma unroll
  for (int d3 = 0; d3 < 128; ++d3) g[d3] = 0.f;
  for (int jm = 0; jm < n; ++jm) {
    int j = list_s[jm];
    uint32_t word = adj_s[tid][j >> 5];
    float a = 0.0f;
    if ((word >> (j & 31)) & 1u) {
      float e = e1d_i + e1s_s[j];
      e = fmaxf(e, 0.2f * e);
      a = __expf(e - m1) * rden;
    }
    #pragma unroll
    for (int d3 = 0; d3 < 128; ++d3) g[d3] += a * hw_s[jm][d3];
  }
  #pragma unroll
  for (int d3 = 0; d3 < 128; ++d3) g[d3] = fmaxf(g[d3] + b1_s[d3], 0.0f);
  // layer-2 e-dots (hW2 never materialized)
  float e2d = 0.f, e2s = 0.f;
  #pragma unroll
  for (int d3 = 0; d3 < 128; ++d3) { e2d += g[d3] * ud2_s[d3]; e2s += g[d3] * us2_s[d3]; }
  e2d_s[tid] = e2d; e2s_s[tid] = e2s;
  __syncthreads();
  float m2 = -1e30f;
  for (int t = 0; t < dg; ++t) {
    int j = nbr_s[tid][t];
    float e = e2d + e2s_s[j];
    e = fmaxf(e, 0.2f * e);
    m2 = fmaxf(m2, e);
  }
  float den2 = 0.f;
  for (int t = 0; t < dg; ++t) {
    int j = nbr_s[tid][t];
    float e = e2d + e2s_s[j];
    e = fmaxf(e, 0.2f * e);
    den2 += __expf(e - m2);
  }
  m2_s[tid] = m2; dr2_s[tid] = 1.0f / den2;
  __syncthreads();
  // column weights w_j = sum_i alpha2[i,j]  (adjacency is symmetric)
  float wj = 0.f;
  for (int t = 0; t < dg; ++t) {
    int i2 = nbr_s[tid][t];
    float e = e2d_s[i2] + e2s;
    e = fmaxf(e, 0.2f * e);
    wj += __expf(e - m2_s[i2]) * dr2_s[i2];
  }
  // t = sum_j wj * g1[j,:]  via wave reduction
  int lane = tid & 63, wv = tid >> 6;
  #pragma unroll
  for (int d3 = 0; d3 < 128; ++d3) {
    float v = wj * g[d3];
    v += __shfl_xor(v, 1);
    v += __shfl_xor(v, 2);
    v += __shfl_xor(v, 4);
    v += __shfl_xor(v, 8);
    v += __shfl_xor(v, 16);
    v += __shfl_xor(v, 32);
    if (lane == 0) t4[wv][d3] = v;
  }
  __syncthreads();
  if (tid < 128) t_s[tid] = t4[0][tid] + t4[1][tid] + t4[2][tid] + t4[3][tid];
  __syncthreads();
  if (tid < 64) {
    float s = 256.0f * b2[c * 64 + tid];
    for (int d3 = 0; d3 < 128; ++d3) s += t_s[d3] * W2[((long)c * 128 + d3) * 64 + tid];
    svec[tid] = s;
  }
  __syncthreads();
  if (tid < 6) {
    float lg = 256.0f * bl[c * 6 + tid];
    for (int f = 0; f < 64; ++f) lg += svec[f] * Wl[((long)c * 64 + f) * 6 + tid];
    lvec[tid] = lg;
  }
  __syncthreads();
  if (tid == 0) {
    float mm = lvec[0];
    for (int k2 = 1; k2 < 6; ++k2) mm = fmaxf(mm, lvec[k2]);
    float ss = 0.f;
    for (int k2 = 0; k2 < 6; ++k2) ss += __expf(lvec[k2] - mm);
    float lse = mm + __logf(ss);
    for (int k2 = 0; k2 < 6; ++k2) out[((long)c * 256 + b) * 6 + k2] = lvec[k2] - lse;
  }
}

// ---------------------------------------------------------------------------
extern "C" void kernel_launch(void* const* d_in, const int* in_sizes, int n_in,
                              void* d_out, int out_size, void* d_ws, size_t ws_size,
                              hipStream_t stream)
{
  const float* vis   = (const float*)d_in[0];
  const float* basic = (const float*)d_in[1];
  const float* cruc  = (const float*)d_in[2];
  const float* Wtb   = (const float*)d_in[3];
  const float* btb   = (const float*)d_in[4];
  const float* Wtk   = (const float*)d_in[5];
  const float* btk   = (const float*)d_in[6];
  const float* Wq    = (const float*)d_in[7];
  const float* bq    = (const float*)d_in[8];
  const float* Wk    = (const float*)d_in[9];
  const float* bk    = (const float*)d_in[10];
  const float* Wv    = (const float*)d_in[11];
  const float* bv    = (const float*)d_in[12];
  const float* Wo    = (const float*)d_in[13];
  const float* bo    = (const float*)d_in[14];
  const float* W1    = (const float*)d_in[15];
  const float* a1s   = (const float*)d_in[16];
  const float* a1d   = (const float*)d_in[17];
  const float* b1    = (const float*)d_in[18];
  const float* W2    = (const float*)d_in[19];
  const float* a2s   = (const float*)d_in[20];
  const float* a2d   = (const float*)d_in[21];
  const float* b2    = (const float*)d_in[22];
  const float* Wl    = (const float*)d_in[23];
  const float* bl    = (const float*)d_in[24];
  const void*  adj   = d_in[25];
  const int*   mask  = (const int*)d_in[26];
  float* out = (float*)d_out;
  char* ws = (char*)d_ws;

  float*    Qw  = (float*)(ws + 0);          // 262144
  uint32_t* ADJ = (uint32_t*)(ws + 262144);  // 8192
  int*      CLS = (int*)(ws + 270336);       // 1024
  int*      LST = (int*)(ws + 271360);       // 2560
  int*      CNT = (int*)(ws + 273920);       // 64
  int*      DEG = (int*)(ws + 273984);       // 1024
  uint8_t*  NBR = (uint8_t*)(ws + 275008);   // 16384
  float*    UD2 = (float*)(ws + 291392);     // 5120
  float*    US2 = (float*)(ws + 296512);     // 5120
  float*    E1D = (float*)(ws + 301632);     // 262144
  float*    E1S = (float*)(ws + 563776);     // 262144
  uint16_t* KX  = (uint16_t*)(ws + 825920);  // 8388608
  uint16_t* VX  = (uint16_t*)(ws + 9214528); // 8388608
  uint16_t* EMB = (uint16_t*)(ws + 17603136);// 33554432
  uint16_t* HW1 = (uint16_t*)(ws + 51157568);// 16777216  -> total ~64.8 MiB

  hipLaunchKernelGGL(k_prep, dim3(11), dim3(256), 0, stream,
                     adj, mask, W2, a2s, a2d, ADJ, CLS, LST, CNT, DEG, NBR, UD2, US2);
  hipLaunchKernelGGL(k_ruleq, dim3(256), dim3(256), 0, stream,
                     basic, cruc, Wtb, btb, Wtk, btk, Wq, bq, Qw);
  hipLaunchKernelGGL(k_kvproj, dim3(1024), dim3(256), 0, stream,
                     vis, Wk, bk, Wv, bv, KX, VX);
  hipLaunchKernelGGL(k_attn, dim3(512), dim3(128), 0, stream, Qw, KX, VX, EMB);
  hipLaunchKernelGGL(k_wo, dim3(2048), dim3(256), 0, stream, EMB, Wo, bo);
  hipLaunchKernelGGL(k_hw1, dim3(2560), dim3(128), 0, stream,
                     EMB, W1, a1d, a1s, LST, CNT, HW1, E1D, E1S);
  hipLaunchKernelGGL(k_gat, dim3(2560), dim3(256), 0, stream,
                     HW1, E1D, E1S, ADJ, CLS, LST, CNT, DEG, NBR,
                     b1, UD2, US2, W2, b2, Wl, bl, out);
}